// Round 8
// baseline (243.291 us; speedup 1.0000x reference)
//
#include <hip/hip_runtime.h>

// Spatial correlation (cost volume), B=8 C=128 H=W=96, patch 9x9, 3x3 box, pad 1.
// out[b,di,dj,y,x] = sum_{i,j in 0..2} P[b,di,dj,y+i,x+j]
// P[b,di,dj,y',x'] = sum_c q_pad[y',x'] * k_pad[y'+di, x'+dj]   (padded 98x98 grid)
//
// R9: R8 (atomic-free stores) confirmed the atomic theory: 352 -> 134 us,
// WRITE 251 -> 33.5 MB. Now the dominant fixable term is DS-read volume:
// with 8 waves x 10-11 offsets, every wave straddles 2 di rows and reads
// 2 full kd windows (6 b128/ch) using only ~half of each. This version uses
// 9 waves (576 thr); wave w owns exactly patch row di=w (9 dj offsets):
// per channel 1 q b128 + 3 kd b128 -> 36 FMAs, every kd float feeds all
// 9 dj. DS reads/block 6144 -> 4608 b128 (-25%), FMA:read 6:1 -> 9:1.
// Bonus: k chunk (576 floats) == one channel tile (24x24), so k staging
// needs ONE precomputed offset + per-chunk channel stride; single run body
// (no per-wave templates). Bank analysis: q(16)/k(24) strides give exactly
// 2-per-bank uniform quarter-wave access -> reads conflict-free; the
// 2.3-2.6e7 conflict counter tracks DMA LDS-writes (doubled in R6 when DMA
// overlapped reads, strides unchanged) -> padding is a dead end; counter
// predicted ~flat here.
// Kept from R8: direct-to-LDS async staging (wave-uniform dest base),
// runtime-indexed double buffer, one barrier per pass, plain predicated
// stores (one block owns one tile, all 128 channels), XCD swizzle b->XCD b.

#define BATCH 8
#define CHN   128
#define IMG   96
#define IMG2  (IMG * IMG)   // 9216
#define TILE  16            // P-tile edge (padded-grid points) per block
#define OTILE 14            // output-tile edge per block (TILE - 2)
#define NC    8             // channels staged per pass
#define NCB   (CHN / NC)    // 16 passes
#define KT    24            // k-tile edge (TILE + 8)
#define NTHR  576           // 9 waves; wave w owns patch row di = w
#define NBLK  (7 * 7 * BATCH)   // 392 = 8 XCDs * 49

#define QFL   (NC * TILE * TILE)   // 2048 q floats per buffer
#define KFL   (NC * KT * KT)       // 4608 k floats per buffer

struct Tiles {
  float qs[NC][TILE][TILE];  //  8192 B (4 chunks of 576; last partial: 320)
  float ks[NC][KT][KT];      // 18432 B (8 chunks of 576 = exactly 1 channel each)
};                           // 26624 B; t[2] = 53248 B -> 2-3 blocks/CU

__device__ __forceinline__ void async_ld4(const float* g, float* l) {
  __builtin_amdgcn_global_load_lds((const __attribute__((address_space(1))) unsigned int*)g,
                                   (__attribute__((address_space(3))) unsigned int*)l,
                                   4, 0, 0);
}

// Issue one pass's staging loads straight to LDS.
// LDS dest is the WAVE base; HW writes active lane l at base + 4*l.
__device__ __forceinline__ void issue_stage(const float* __restrict__ qcb,
                                            const float* __restrict__ kcb,
                                            Tiles& tb, const int (&qoff)[4],
                                            int koff, unsigned qm, bool kok, int tid) {
  float* qf = &tb.qs[0][0][0] + (tid & ~63);   // wave-uniform base
  float* kf = &tb.ks[0][0][0] + (tid & ~63);
#pragma unroll
  for (int i = 0; i < 4; ++i)
    if (qm & (1u << i)) async_ld4(qcb + qoff[i], qf + i * NTHR);
  if (kok) {
#pragma unroll
    for (int i = 0; i < 8; ++i)
      async_ld4(kcb + (size_t)i * IMG2 + koff, kf + i * NTHR);
  }
}

__global__ __launch_bounds__(NTHR, 5) void spatial_corr_kernel(const float* __restrict__ q,
                                                               const float* __restrict__ k,
                                                               float* __restrict__ out) {
  __shared__ Tiles t[2];
  const int tid  = threadIdx.x;
  const int w    = tid >> 6;        // 0..8 = owned patch row di
  const int lane = tid & 63;

  // XCD swizzle: 392 = 8 * 49; XCD g owns all 49 tiles of batch g
  // -> q/k of one batch hot in that XCD's 4MB L2 (FETCH 142->41MB measured).
  int id = blockIdx.x;
  id = (id & 7) * 49 + (id >> 3);
  const int bx = id % 7; id /= 7;
  const int by = id % 7; id /= 7;
  const int b  = id;                // 0..7
  const int X0 = bx * OTILE;
  const int Y0 = by * OTILE;

  // ---- Precompute per-thread staging offsets + validity masks ONCE. ----
  unsigned qm = 0;
  int qoff[4];
#pragma unroll
  for (int i = 0; i < 4; ++i) {
    const int s = i * NTHR + tid;                // flat q slot
    const int c = s >> 8, rem = s & 255, rr = rem >> 4, col = rem & 15;
    const int gy = Y0 + rr - 1, gx = X0 + col - 1;
    qoff[i] = c * IMG2 + gy * IMG + gx;
    const bool ok = (s < QFL) && ((unsigned)gy < IMG) && ((unsigned)gx < IMG);
    if (ok) qm |= 1u << i; else qoff[i] = 0;
  }
  const int kr = tid / KT, kc = tid - kr * KT;   // k chunk == one 24x24 channel
  const int kgy = Y0 + kr - 5, kgx = X0 + kc - 5;
  const bool kok = ((unsigned)kgy < IMG) && ((unsigned)kgx < IMG);
  const int koff = kok ? (kgy * IMG + kgx) : 0;

  // Zero never-loaded (OOB) LDS slots once, both buffers (interior: no-op).
  {
    float* qf0 = &t[0].qs[0][0][0]; float* qf1 = &t[1].qs[0][0][0];
    float* kf0 = &t[0].ks[0][0][0]; float* kf1 = &t[1].ks[0][0][0];
#pragma unroll
    for (int i = 0; i < 4; ++i) {
      const int s = i * NTHR + tid;
      if (s < QFL && !(qm & (1u << i))) { qf0[s] = 0.f; qf1[s] = 0.f; }
    }
    if (!kok) {
#pragma unroll
      for (int i = 0; i < 8; ++i) { kf0[i * NTHR + tid] = 0.f; kf1[i * NTHR + tid] = 0.f; }
    }
  }

  const float* qb = q + (size_t)b * CHN * IMG2;
  const float* kb = k + (size_t)b * CHN * IMG2;

  const int xg  = lane & 3;    // 4 x-groups of 4 points = 16 cols
  const int py  = lane >> 2;   // 16 rows
  const int xg4 = xg * 4;

  float acc[36];
#pragma unroll
  for (int i = 0; i < 36; ++i) acc[i] = 0.f;

  // Prologue: fill buffer 0 (async); barrier drains vmcnt + publishes zeros.
  issue_stage(qb, kb, t[0], qoff, koff, qm, kok, tid);
  __syncthreads();

  for (int cb = 0; cb < NCB; ++cb) {
    // Next pass's direct-to-LDS loads stay in flight across this compute
    // phase; drained by the pre-barrier vmcnt(0) inside __syncthreads.
    if (cb + 1 < NCB)
      issue_stage(qb + (size_t)(cb + 1) * NC * IMG2,
                  kb + (size_t)(cb + 1) * NC * IMG2,
                  t[(cb + 1) & 1], qoff, koff, qm, kok, tid);
    const Tiles& tc = t[cb & 1];
#pragma unroll 2
    for (int c = 0; c < NC; ++c) {
      float qa[4];
      *(float4*)qa = *(const float4*)&tc.qs[c][py][xg4];
      float kd[12];                      // row di=w, cols xg4 .. xg4+11
      *(float4*)&kd[0] = *(const float4*)&tc.ks[c][py + w][xg4 + 0];
      *(float4*)&kd[4] = *(const float4*)&tc.ks[c][py + w][xg4 + 4];
      *(float4*)&kd[8] = *(const float4*)&tc.ks[c][py + w][xg4 + 8];
#pragma unroll
      for (int dj = 0; dj < 9; ++dj)
#pragma unroll
        for (int p = 0; p < 4; ++p)
          acc[dj * 4 + p] = __builtin_fmaf(qa[p], kd[dj + p], acc[dj * 4 + p]);
    }
    __syncthreads();                     // single barrier per pass
  }

  // Epilogue: 3x3 box sum via shuffles; exclusive owner -> plain stores.
  const int srcx = (xg < 3) ? (lane + 1) : lane;   // xg==3 values unused
  const int gy   = Y0 + py;
  const bool rowok = (py < OTILE) && (gy < IMG);
  float* obase = out + ((size_t)b * 81 * IMG + gy) * IMG + X0;
#pragma unroll
  for (int dj = 0; dj < 9; ++dj) {
    const float a0 = acc[dj * 4 + 0], a1 = acc[dj * 4 + 1];
    const float a2 = acc[dj * 4 + 2], a3 = acc[dj * 4 + 3];
    const float a0n = __shfl(a0, srcx);
    const float a1n = __shfl(a1, srcx);
    float s0 = a0 + a1 + a2;
    float s1 = a1 + a2 + a3;
    float s2 = a2 + a3 + a0n;
    float s3 = a3 + a0n + a1n;
    s0 += __shfl_down(s0, 4) + __shfl_down(s0, 8);
    s1 += __shfl_down(s1, 4) + __shfl_down(s1, 8);
    s2 += __shfl_down(s2, 4) + __shfl_down(s2, 8);
    s3 += __shfl_down(s3, 4) + __shfl_down(s3, 8);
    if (rowok) {
      const int o = w * 9 + dj;
      float* orow = obase + (size_t)o * IMG2;
      if (xg4 + 0 < OTILE && X0 + xg4 + 0 < IMG) orow[xg4 + 0] = s0;
      if (xg4 + 1 < OTILE && X0 + xg4 + 1 < IMG) orow[xg4 + 1] = s1;
      if (xg4 + 2 < OTILE && X0 + xg4 + 2 < IMG) orow[xg4 + 2] = s2;
      if (xg4 + 3 < OTILE && X0 + xg4 + 3 < IMG) orow[xg4 + 3] = s3;
    }
  }
}

extern "C" void kernel_launch(void* const* d_in, const int* in_sizes, int n_in,
                              void* d_out, int out_size, void* d_ws, size_t ws_size,
                              hipStream_t stream) {
  const float* q = (const float*)d_in[0];
  const float* k = (const float*)d_in[1];
  // d_in[2] (value) is unused by the reference output.
  float* out = (float*)d_out;
  // Every output element has exactly one writer -> no memset, no atomics.
  dim3 grid(NBLK);
  dim3 block(NTHR);
  hipLaunchKernelGGL(spatial_corr_kernel, grid, block, 0, stream, q, k, out);
}